// Round 5
// baseline (456.168 us; speedup 1.0000x reference)
//
#include <hip/hip_runtime.h>
#include <cstdint>

typedef unsigned short u16;   // bf16 bit pattern
typedef unsigned int   u32;
typedef __attribute__((ext_vector_type(8))) __bf16 bf16x8;
typedef __attribute__((ext_vector_type(4))) float  f32x4;

#define N_IMG 4
#define C_DIM 256
#define H_DIM 128
#define W_DIM 128
#define HW    (H_DIM * W_DIM)      // 16384
#define M_TOT (N_IMG * HW)         // 65536
#define CG    64
#define PADOFF 112
#define EPSV  1e-5f

__device__ __forceinline__ u16 f2b(float f) {
  u32 u = __float_as_uint(f);
  u += 0x7fffu + ((u >> 16) & 1u);   // round-to-nearest-even
  return (u16)(u >> 16);
}

// cast n f32 -> n bf16, 4 elems/thread
__global__ __launch_bounds__(256) void cast_w(const float* __restrict__ in,
                                              u16* __restrict__ out, int n4) {
  int i = blockIdx.x * 256 + threadIdx.x;
  if (i >= n4) return;
  f32x4 v = reinterpret_cast<const f32x4*>(in)[i];
  u32 lo = (u32)f2b(v[0]) | ((u32)f2b(v[1]) << 16);
  u32 hi = (u32)f2b(v[2]) | ((u32)f2b(v[3]) << 16);
  reinterpret_cast<u32*>(out)[2 * i]     = lo;
  reinterpret_cast<u32*>(out)[2 * i + 1] = hi;
}

// per batch z: in f32 (C, HW) -> out bf16 (HW, C)
__global__ __launch_bounds__(256) void nchw_to_nhwc(const float* __restrict__ in,
                                                    u16* __restrict__ out) {
  __shared__ float tile[64][65];
  const int z = blockIdx.z;
  in  += (size_t)z * C_DIM * HW;
  out += (size_t)z * HW * C_DIM;
  const int p0 = blockIdx.x * 64;   // pixel tile
  const int c0 = blockIdx.y * 64;   // channel tile
  const int t = threadIdx.x;
  const int col = t & 63, rb = t >> 6;
#pragma unroll
  for (int i = 0; i < 16; ++i) {
    int row = rb + i * 4;           // channel within tile
    tile[row][col] = in[(size_t)(c0 + row) * HW + p0 + col];
  }
  __syncthreads();
  const int c = t & 63, pb = t >> 6;
#pragma unroll
  for (int i = 0; i < 16; ++i) {
    int p = pb + i * 4;             // pixel within tile
    out[(size_t)(p0 + p) * C_DIM + c0 + c] = f2b(tile[c][p]);
  }
}

// per batch z: in bf16 (HW, C) -> out f32 (C, HW)   [final output store]
__global__ __launch_bounds__(256) void nhwc_to_nchw_f32(const u16* __restrict__ in,
                                                        float* __restrict__ out) {
  __shared__ float tile[64][65];
  const int z = blockIdx.z;
  in  += (size_t)z * HW * C_DIM;
  out += (size_t)z * C_DIM * HW;
  const int c0 = blockIdx.x * 64;   // channel tile
  const int r0 = blockIdx.y * 64;   // pixel tile
  const int t = threadIdx.x;
  const int colu = t & 31, rbase = t >> 5;
#pragma unroll
  for (int i = 0; i < 8; ++i) {
    int row = rbase + i * 8;        // pixel within tile
    u32 u = *reinterpret_cast<const u32*>(in + (size_t)(r0 + row) * C_DIM + c0 + colu * 2);
    tile[row][colu * 2]     = __uint_as_float(u << 16);
    tile[row][colu * 2 + 1] = __uint_as_float(u & 0xffff0000u);
  }
  __syncthreads();
  const int rr = t & 63, cb = t >> 6;
#pragma unroll
  for (int i = 0; i < 16; ++i) {
    int cc = cb + i * 4;            // channel within tile
    out[(size_t)(c0 + cc) * HW + r0 + rr] = tile[rr][cc];
  }
}

// ---------------------------------------------------------------------------
// GEMM: C[m,n] = epilogue( sum_k A[m,k]*B[n,k] )
// A: (M,K) bf16 row-major, B: (N,K) bf16 row-major. 128x128 tile, BK=32,
// 16x16x32 MFMA, register->LDS staging (verified: agrees with VALU build).
// MODE 0: bn+silu   MODE 1: +bias   MODE 2: +bias,bn,silu  (params f32)
// ---------------------------------------------------------------------------
template <int MODE, typename OT>
__global__ __launch_bounds__(256) void gemm_ep(
    const u16* __restrict__ A, const u16* __restrict__ B, OT* __restrict__ Cmat,
    int K, int Nreal,
    const float* __restrict__ bias, const float* __restrict__ gamma,
    const float* __restrict__ beta, const float* __restrict__ mean,
    const float* __restrict__ var) {
  constexpr int BM = 128, BK = 32;
  __shared__ __align__(16) u16 As[BM * BK];
  __shared__ __align__(16) u16 Bs[BM * BK];
  const int tid  = threadIdx.x;
  const int lane = tid & 63;
  const int wave = tid >> 6;
  const int quad = lane >> 4;
  const int l16  = lane & 15;
  const int bm = blockIdx.x * BM;
  const int bn = blockIdx.y * BM;
  const int wm = (wave & 1) * 64;
  const int wn = (wave >> 1) * 64;

  f32x4 acc[4][4] = {};

  for (int ko = 0; ko < K; ko += BK) {
    bf16x8 ra[2], rb[2];
#pragma unroll
    for (int it = 0; it < 2; ++it) {
      int chunk = it * 256 + tid;          // 16B chunk id, 512 per tile
      int r  = chunk >> 2;                 // tile row 0..127
      int kk = (chunk & 3) << 3;           // k offset 0,8,16,24
      ra[it] = *reinterpret_cast<const bf16x8*>(A + (size_t)(bm + r) * K + (ko + kk));
      int br = bn + r; if (br >= Nreal) br = Nreal - 1;   // clamp (N=112 case)
      rb[it] = *reinterpret_cast<const bf16x8*>(B + (size_t)br * K + (ko + kk));
    }
    __syncthreads();   // previous iteration's LDS reads done before overwrite
#pragma unroll
    for (int it = 0; it < 2; ++it) {
      int chunk = it * 256 + tid;
      reinterpret_cast<bf16x8*>(As)[chunk] = ra[it];
      reinterpret_cast<bf16x8*>(Bs)[chunk] = rb[it];
    }
    __syncthreads();
    const bf16x8* Ap = reinterpret_cast<const bf16x8*>(As);
    const bf16x8* Bp = reinterpret_cast<const bf16x8*>(Bs);
    bf16x8 af[4], bfr[4];
#pragma unroll
    for (int mi = 0; mi < 4; ++mi) af[mi] = Ap[(wm + mi * 16 + l16) * 4 + quad];
#pragma unroll
    for (int ni = 0; ni < 4; ++ni) bfr[ni] = Bp[(wn + ni * 16 + l16) * 4 + quad];
#pragma unroll
    for (int mi = 0; mi < 4; ++mi)
#pragma unroll
      for (int ni = 0; ni < 4; ++ni)
        acc[mi][ni] = __builtin_amdgcn_mfma_f32_16x16x32_bf16(
            af[mi], bfr[ni], acc[mi][ni], 0, 0, 0);
  }

#pragma unroll
  for (int ni = 0; ni < 4; ++ni) {
    int n  = bn + wn + ni * 16 + l16;
    int nc = n < Nreal ? n : 0;
    float s = 1.f, sh = 0.f;
    if constexpr (MODE == 0) {
      float sc = gamma[nc] * rsqrtf(var[nc] + EPSV);
      s = sc; sh = beta[nc] - mean[nc] * sc;
    } else if constexpr (MODE == 1) {
      sh = bias[nc];
    } else {
      float sc = gamma[nc] * rsqrtf(var[nc] + EPSV);
      s = sc; sh = (beta[nc] - mean[nc] * sc) + bias[nc] * sc;
    }
    bool ok = (n < Nreal);
#pragma unroll
    for (int mi = 0; mi < 4; ++mi) {
      int mrow = bm + wm + mi * 16 + quad * 4;
#pragma unroll
      for (int i = 0; i < 4; ++i) {
        float y = acc[mi][ni][i] * s + sh;
        if constexpr (MODE != 1) y = y / (1.f + __expf(-y));   // silu
        if (ok) {
          size_t o = (size_t)(mrow + i) * Nreal + n;
          if constexpr (sizeof(OT) == 4) Cmat[o] = y;
          else                           Cmat[o] = f2b(y);
        }
      }
    }
  }
}

// ---------------------------------------------------------------------------
// Deformable sampling. Half-wave (32 lanes) per (pixel m, group g); lane = 2
// consecutive channels (4B loads -> 128B coalesced per corner).
// v: (M, C) NHWC bf16 ; om: (M, 112) f32 [per g: 18 offsets(x,y), 9 masks]
// ---------------------------------------------------------------------------
__global__ __launch_bounds__(256) void dcn_sample(
    const u16* __restrict__ v, const float* __restrict__ om,
    u16* __restrict__ outp) {
  int idx = blockIdx.x * 256 + threadIdx.x;
  const int c2 = idx & 31;
  const int g  = (idx >> 5) & 3;
  const int m  = idx >> 7;
  const int n  = m >> 14;            // HW = 2^14
  const int hw = m & (HW - 1);
  const int h = hw >> 7, w = hw & 127;
  const float* p = om + (size_t)m * PADOFF + g * 27;
  const u16* vb = v + (size_t)n * HW * C_DIM + g * CG + (c2 << 1);
  float a0 = 0.f, a1 = 0.f;
#pragma unroll
  for (int k = 0; k < 9; ++k) {
    const int di = k / 3 - 1, dj = k % 3 - 1;
    float ox = p[2 * k], oy = p[2 * k + 1], mk = p[18 + k];
    float lh = (float)(h + di) + oy;
    float lw = (float)(w + dj) + ox;
    float fh = floorf(lh), fw = floorf(lw);
    float dh = lh - fh, dw = lw - fw;
    int h0 = (int)fh, w0 = (int)fw;
    float w00 = (1.f - dh) * (1.f - dw) * mk;
    float w01 = (1.f - dh) * dw * mk;
    float w10 = dh * (1.f - dw) * mk;
    float w11 = dh * dw * mk;
#pragma unroll
    for (int cy = 0; cy < 2; ++cy)
#pragma unroll
      for (int cx = 0; cx < 2; ++cx) {
        int hh = h0 + cy, ww = w0 + cx;
        float wt = cy ? (cx ? w11 : w10) : (cx ? w01 : w00);
        if (hh >= 0 && hh < H_DIM && ww >= 0 && ww < W_DIM) {
          u32 u = *reinterpret_cast<const u32*>(vb + ((size_t)(hh << 7) + ww) * C_DIM);
          a0 += wt * __uint_as_float(u << 16);
          a1 += wt * __uint_as_float(u & 0xffff0000u);
        }
      }
  }
  u32 r = (u32)f2b(a0) | ((u32)f2b(a1) << 16);
  *reinterpret_cast<u32*>(outp + (size_t)m * C_DIM + g * CG + (c2 << 1)) = r;
}

// ---------------------------------------------------------------------------
extern "C" void kernel_launch(void* const* d_in, const int* in_sizes, int n_in,
                              void* d_out, int out_size, void* d_ws, size_t ws_size,
                              hipStream_t stream) {
  const float* x        = (const float*)d_in[0];
  const float* conv_w   = (const float*)d_in[1];
  const float* bn1_g    = (const float*)d_in[2];
  const float* bn1_b    = (const float*)d_in[3];
  const float* bn1_m    = (const float*)d_in[4];
  const float* bn1_v    = (const float*)d_in[5];
  const float* value_w  = (const float*)d_in[6];
  const float* value_b  = (const float*)d_in[7];
  const float* offset_w = (const float*)d_in[8];
  const float* offset_b = (const float*)d_in[9];
  const float* out_w    = (const float*)d_in[10];
  const float* out_b    = (const float*)d_in[11];
  const float* bn2_g    = (const float*)d_in[12];
  const float* bn2_b    = (const float*)d_in[13];
  const float* bn2_m    = (const float*)d_in[14];
  const float* bn2_v    = (const float*)d_in[15];

  char* ws = (char*)d_ws;
  u16*   xt   = (u16*)(ws);                    // 32 MiB  (x NHWC bf16)
  u16*   t    = (u16*)(ws + 33554432);         // 32 MiB  (post conv+bn1+silu)
  u16*   vv   = (u16*)(ws + 67108864);         // 32 MiB  (value proj)
  float* om   = (float*)(ws + 100663296);      // 28 MiB  (offset+mask f32)
  u16*   wc   = (u16*)(ws + 130023424);        // conv_w   bf16
  u16*   wv   = (u16*)(ws + 130154496);        // value_w  bf16
  u16*   wo   = (u16*)(ws + 130285568);        // offset_w bf16
  u16*   wout = (u16*)(ws + 130342912);        // out_w    bf16
  u16*   dcn  = xt;                            // reuse (xt dead after K1)
  u16*   otmp = t;                             // reuse (t dead after K3)
  float* outp = (float*)d_out;                 // FINAL OUTPUT IS FLOAT32

  // W: weights f32 -> bf16
  cast_w<<<64, 256, 0, stream>>>(conv_w,   wc,   65536 / 4);
  cast_w<<<64, 256, 0, stream>>>(value_w,  wv,   65536 / 4);
  cast_w<<<28, 256, 0, stream>>>(offset_w, wo,   (PADOFF * C_DIM) / 4);
  cast_w<<<64, 256, 0, stream>>>(out_w,    wout, 65536 / 4);

  // K0: x f32 NCHW -> bf16 NHWC
  nchw_to_nhwc<<<dim3(HW / 64, C_DIM / 64, N_IMG), 256, 0, stream>>>(x, xt);
  // K1: t = silu(bn1(xt @ conv_w^T))
  gemm_ep<0, u16><<<dim3(M_TOT / 128, C_DIM / 128), 256, 0, stream>>>(
      xt, wc, t, C_DIM, C_DIM, nullptr, bn1_g, bn1_b, bn1_m, bn1_v);
  // K2: v = t @ value_w^T + value_b
  gemm_ep<1, u16><<<dim3(M_TOT / 128, C_DIM / 128), 256, 0, stream>>>(
      t, wv, vv, C_DIM, C_DIM, value_b, nullptr, nullptr, nullptr, nullptr);
  // K3: om = t @ offset_w^T + offset_b   (f32, 112 cols)
  gemm_ep<1, float><<<dim3(M_TOT / 128, 1), 256, 0, stream>>>(
      t, wo, om, C_DIM, PADOFF, offset_b, nullptr, nullptr, nullptr, nullptr);
  // K4: deformable bilinear sampling
  dcn_sample<<<dim3(M_TOT * 128 / 256), 256, 0, stream>>>(vv, om, dcn);
  // K5: otmp = silu(bn2(dcn @ out_w^T + out_b))   (bf16 NHWC)
  gemm_ep<2, u16><<<dim3(M_TOT / 128, C_DIM / 128), 256, 0, stream>>>(
      dcn, wout, otmp, C_DIM, C_DIM, out_b, bn2_g, bn2_b, bn2_m, bn2_v);
  // K6: bf16 NHWC -> f32 NCHW (d_out)
  nhwc_to_nchw_f32<<<dim3(C_DIM / 64, HW / 64, N_IMG), 256, 0, stream>>>(otmp, outp);
}

// Round 6
// 315.025 us; speedup vs baseline: 1.4480x; 1.4480x over previous
//
#include <hip/hip_runtime.h>
#include <cstdint>

typedef unsigned short u16;   // bf16 bit pattern
typedef unsigned int   u32;
typedef __attribute__((ext_vector_type(8))) __bf16 bf16x8;
typedef __attribute__((ext_vector_type(4))) float  f32x4;
typedef __attribute__((ext_vector_type(4))) u32    u32x4;

#define N_IMG 4
#define C_DIM 256
#define H_DIM 128
#define W_DIM 128
#define HW    (H_DIM * W_DIM)      // 16384
#define M_TOT (N_IMG * HW)         // 65536
#define CG    64
#define PADOFF 112
#define EPSV  1e-5f

__device__ __forceinline__ u16 f2b(float f) {
  u32 u = __float_as_uint(f);
  u += 0x7fffu + ((u >> 16) & 1u);   // round-to-nearest-even
  return (u16)(u >> 16);
}

// cast n f32 -> n bf16, 4 elems/thread
__global__ __launch_bounds__(256) void cast_w(const float* __restrict__ in,
                                              u16* __restrict__ out, int n4) {
  int i = blockIdx.x * 256 + threadIdx.x;
  if (i >= n4) return;
  f32x4 v = reinterpret_cast<const f32x4*>(in)[i];
  u32 lo = (u32)f2b(v[0]) | ((u32)f2b(v[1]) << 16);
  u32 hi = (u32)f2b(v[2]) | ((u32)f2b(v[3]) << 16);
  reinterpret_cast<u32*>(out)[2 * i]     = lo;
  reinterpret_cast<u32*>(out)[2 * i + 1] = hi;
}

// per batch z: in f32 (C, HW) -> out bf16 (HW, C)
__global__ __launch_bounds__(256) void nchw_to_nhwc(const float* __restrict__ in,
                                                    u16* __restrict__ out) {
  __shared__ float tile[64][65];
  const int z = blockIdx.z;
  in  += (size_t)z * C_DIM * HW;
  out += (size_t)z * HW * C_DIM;
  const int p0 = blockIdx.x * 64;   // pixel tile
  const int c0 = blockIdx.y * 64;   // channel tile
  const int t = threadIdx.x;
  const int col = t & 63, rb = t >> 6;
#pragma unroll
  for (int i = 0; i < 16; ++i) {
    int row = rb + i * 4;           // channel within tile
    tile[row][col] = in[(size_t)(c0 + row) * HW + p0 + col];
  }
  __syncthreads();
  const int c = t & 63, pb = t >> 6;
#pragma unroll
  for (int i = 0; i < 16; ++i) {
    int p = pb + i * 4;             // pixel within tile
    out[(size_t)(p0 + p) * C_DIM + c0 + c] = f2b(tile[c][p]);
  }
}

// per batch z: in bf16 (HW, C) -> out f32 (C, HW)   [final output store]
__global__ __launch_bounds__(256) void nhwc_to_nchw_f32(const u16* __restrict__ in,
                                                        float* __restrict__ out) {
  __shared__ float tile[64][65];
  const int z = blockIdx.z;
  in  += (size_t)z * HW * C_DIM;
  out += (size_t)z * C_DIM * HW;
  const int c0 = blockIdx.x * 64;   // channel tile
  const int r0 = blockIdx.y * 64;   // pixel tile
  const int t = threadIdx.x;
  const int colu = t & 31, rbase = t >> 5;
#pragma unroll
  for (int i = 0; i < 8; ++i) {
    int row = rbase + i * 8;        // pixel within tile
    u32 u = *reinterpret_cast<const u32*>(in + (size_t)(r0 + row) * C_DIM + c0 + colu * 2);
    tile[row][colu * 2]     = __uint_as_float(u << 16);
    tile[row][colu * 2 + 1] = __uint_as_float(u & 0xffff0000u);
  }
  __syncthreads();
  const int rr = t & 63, cb = t >> 6;
#pragma unroll
  for (int i = 0; i < 16; ++i) {
    int cc = cb + i * 4;            // channel within tile
    out[(size_t)(c0 + cc) * HW + r0 + rr] = tile[rr][cc];
  }
}

// ---------------------------------------------------------------------------
// GEMM: C[m,n] = epilogue( sum_k A[m,k]*B[n,k] )
// A: (M,K) bf16 row-major, B: (N,K) bf16 row-major. 128x128 tile, BK=32,
// 16x16x32 MFMA, register->LDS staging (verified: agrees with VALU build).
// MODE 0: bn+silu   MODE 1: +bias   MODE 2: +bias,bn,silu  (params f32)
// ---------------------------------------------------------------------------
template <int MODE, typename OT>
__global__ __launch_bounds__(256) void gemm_ep(
    const u16* __restrict__ A, const u16* __restrict__ B, OT* __restrict__ Cmat,
    int K, int Nreal,
    const float* __restrict__ bias, const float* __restrict__ gamma,
    const float* __restrict__ beta, const float* __restrict__ mean,
    const float* __restrict__ var) {
  constexpr int BM = 128, BK = 32;
  __shared__ __align__(16) u16 As[BM * BK];
  __shared__ __align__(16) u16 Bs[BM * BK];
  const int tid  = threadIdx.x;
  const int lane = tid & 63;
  const int wave = tid >> 6;
  const int quad = lane >> 4;
  const int l16  = lane & 15;
  const int bm = blockIdx.x * BM;
  const int bn = blockIdx.y * BM;
  const int wm = (wave & 1) * 64;
  const int wn = (wave >> 1) * 64;

  f32x4 acc[4][4] = {};

  for (int ko = 0; ko < K; ko += BK) {
    bf16x8 ra[2], rb[2];
#pragma unroll
    for (int it = 0; it < 2; ++it) {
      int chunk = it * 256 + tid;          // 16B chunk id, 512 per tile
      int r  = chunk >> 2;                 // tile row 0..127
      int kk = (chunk & 3) << 3;           // k offset 0,8,16,24
      ra[it] = *reinterpret_cast<const bf16x8*>(A + (size_t)(bm + r) * K + (ko + kk));
      int br = bn + r; if (br >= Nreal) br = Nreal - 1;   // clamp (N=112 case)
      rb[it] = *reinterpret_cast<const bf16x8*>(B + (size_t)br * K + (ko + kk));
    }
    __syncthreads();   // previous iteration's LDS reads done before overwrite
#pragma unroll
    for (int it = 0; it < 2; ++it) {
      int chunk = it * 256 + tid;
      reinterpret_cast<bf16x8*>(As)[chunk] = ra[it];
      reinterpret_cast<bf16x8*>(Bs)[chunk] = rb[it];
    }
    __syncthreads();
    const bf16x8* Ap = reinterpret_cast<const bf16x8*>(As);
    const bf16x8* Bp = reinterpret_cast<const bf16x8*>(Bs);
    bf16x8 af[4], bfr[4];
#pragma unroll
    for (int mi = 0; mi < 4; ++mi) af[mi] = Ap[(wm + mi * 16 + l16) * 4 + quad];
#pragma unroll
    for (int ni = 0; ni < 4; ++ni) bfr[ni] = Bp[(wn + ni * 16 + l16) * 4 + quad];
#pragma unroll
    for (int mi = 0; mi < 4; ++mi)
#pragma unroll
      for (int ni = 0; ni < 4; ++ni)
        acc[mi][ni] = __builtin_amdgcn_mfma_f32_16x16x32_bf16(
            af[mi], bfr[ni], acc[mi][ni], 0, 0, 0);
  }

#pragma unroll
  for (int ni = 0; ni < 4; ++ni) {
    int n  = bn + wn + ni * 16 + l16;
    int nc = n < Nreal ? n : 0;
    float s = 1.f, sh = 0.f;
    if constexpr (MODE == 0) {
      float sc = gamma[nc] * rsqrtf(var[nc] + EPSV);
      s = sc; sh = beta[nc] - mean[nc] * sc;
    } else if constexpr (MODE == 1) {
      sh = bias[nc];
    } else {
      float sc = gamma[nc] * rsqrtf(var[nc] + EPSV);
      s = sc; sh = (beta[nc] - mean[nc] * sc) + bias[nc] * sc;
    }
    bool ok = (n < Nreal);
#pragma unroll
    for (int mi = 0; mi < 4; ++mi) {
      int mrow = bm + wm + mi * 16 + quad * 4;
#pragma unroll
      for (int i = 0; i < 4; ++i) {
        float y = acc[mi][ni][i] * s + sh;
        if constexpr (MODE != 1) y = y / (1.f + __expf(-y));   // silu
        if (ok) {
          size_t o = (size_t)(mrow + i) * Nreal + n;
          if constexpr (sizeof(OT) == 4) Cmat[o] = y;
          else                           Cmat[o] = f2b(y);
        }
      }
    }
  }
}

// ---------------------------------------------------------------------------
// Deformable sampling, v2: 8 channels/thread (dwordx4 corner loads), om rows
// staged in LDS (one coalesced block load, broadcast reads), clamp+cndmask
// instead of divergent bounds branches.
// Block = 256 thr = 8 pixels x 4 groups x 8 chan-octs. Grid = M_TOT/8.
// v: (M, C) NHWC bf16 ; om: (M, 112) f32 [per g: 18 offsets(x,y), 9 masks]
// ---------------------------------------------------------------------------
__global__ __launch_bounds__(256) void dcn_sample(
    const u16* __restrict__ v, const float* __restrict__ om,
    u16* __restrict__ outp) {
  __shared__ float sm[8 * PADOFF];
  const int tid = threadIdx.x;
  const int m0  = blockIdx.x * 8;
  {
    const float* src = om + (size_t)m0 * PADOFF;
#pragma unroll
    for (int i = 0; i < 4; ++i) {
      int j = tid + i * 256;
      if (j < 8 * PADOFF) sm[j] = src[j];
    }
  }
  __syncthreads();
  const int c8 = tid & 7;            // 8-channel slice within group
  const int g  = (tid >> 3) & 3;
  const int pl = tid >> 5;           // pixel within block
  const int m  = m0 + pl;
  const int n  = m >> 14;            // HW = 2^14
  const int hw = m & (HW - 1);
  const int h = hw >> 7, w = hw & 127;
  const float* p = sm + pl * PADOFF + g * 27;
  const u16* vb = v + (size_t)n * HW * C_DIM + g * CG + c8 * 8;
  float acc[8] = {};
#pragma unroll
  for (int k = 0; k < 9; ++k) {
    const int di = k / 3 - 1, dj = k % 3 - 1;
    float ox = p[2 * k], oy = p[2 * k + 1], mk = p[18 + k];
    float lh = (float)(h + di) + oy;
    float lw = (float)(w + dj) + ox;
    float fh = floorf(lh), fw = floorf(lw);
    float dh = lh - fh, dw = lw - fw;
    int h0 = (int)fh, w0 = (int)fw;
    float wy[2] = {(1.f - dh) * mk, dh * mk};
    float wx[2] = {1.f - dw, dw};
#pragma unroll
    for (int cy = 0; cy < 2; ++cy)
#pragma unroll
      for (int cx = 0; cx < 2; ++cx) {
        int hh = h0 + cy, ww = w0 + cx;
        bool ok = ((u32)hh < (u32)H_DIM) & ((u32)ww < (u32)W_DIM);
        float wt = ok ? wy[cy] * wx[cx] : 0.f;
        int hc = min(max(hh, 0), H_DIM - 1);
        int wc = min(max(ww, 0), W_DIM - 1);
        u32x4 q = *reinterpret_cast<const u32x4*>(vb + (size_t)((hc << 7) + wc) * C_DIM);
#pragma unroll
        for (int j = 0; j < 4; ++j) {
          acc[2 * j]     += wt * __uint_as_float(q[j] << 16);
          acc[2 * j + 1] += wt * __uint_as_float(q[j] & 0xffff0000u);
        }
      }
  }
  u32x4 r;
#pragma unroll
  for (int j = 0; j < 4; ++j)
    r[j] = (u32)f2b(acc[2 * j]) | ((u32)f2b(acc[2 * j + 1]) << 16);
  *reinterpret_cast<u32x4*>(outp + (size_t)m * C_DIM + g * CG + c8 * 8) = r;
}

// ---------------------------------------------------------------------------
extern "C" void kernel_launch(void* const* d_in, const int* in_sizes, int n_in,
                              void* d_out, int out_size, void* d_ws, size_t ws_size,
                              hipStream_t stream) {
  const float* x        = (const float*)d_in[0];
  const float* conv_w   = (const float*)d_in[1];
  const float* bn1_g    = (const float*)d_in[2];
  const float* bn1_b    = (const float*)d_in[3];
  const float* bn1_m    = (const float*)d_in[4];
  const float* bn1_v    = (const float*)d_in[5];
  const float* value_w  = (const float*)d_in[6];
  const float* value_b  = (const float*)d_in[7];
  const float* offset_w = (const float*)d_in[8];
  const float* offset_b = (const float*)d_in[9];
  const float* out_w    = (const float*)d_in[10];
  const float* out_b    = (const float*)d_in[11];
  const float* bn2_g    = (const float*)d_in[12];
  const float* bn2_b    = (const float*)d_in[13];
  const float* bn2_m    = (const float*)d_in[14];
  const float* bn2_v    = (const float*)d_in[15];

  char* ws = (char*)d_ws;
  u16*   xt   = (u16*)(ws);                    // 32 MiB  (x NHWC bf16)
  u16*   t    = (u16*)(ws + 33554432);         // 32 MiB  (post conv+bn1+silu)
  u16*   vv   = (u16*)(ws + 67108864);         // 32 MiB  (value proj)
  float* om   = (float*)(ws + 100663296);      // 28 MiB  (offset+mask f32)
  u16*   wc   = (u16*)(ws + 130023424);        // conv_w   bf16
  u16*   wv   = (u16*)(ws + 130154496);        // value_w  bf16
  u16*   wo   = (u16*)(ws + 130285568);        // offset_w bf16
  u16*   wout = (u16*)(ws + 130342912);        // out_w    bf16
  u16*   dcn  = xt;                            // reuse (xt dead after K1)
  u16*   otmp = t;                             // reuse (t dead after K3)
  float* outp = (float*)d_out;                 // final output is f32

  // W: weights f32 -> bf16
  cast_w<<<64, 256, 0, stream>>>(conv_w,   wc,   65536 / 4);
  cast_w<<<64, 256, 0, stream>>>(value_w,  wv,   65536 / 4);
  cast_w<<<28, 256, 0, stream>>>(offset_w, wo,   (PADOFF * C_DIM) / 4);
  cast_w<<<64, 256, 0, stream>>>(out_w,    wout, 65536 / 4);

  // K0: x f32 NCHW -> bf16 NHWC
  nchw_to_nhwc<<<dim3(HW / 64, C_DIM / 64, N_IMG), 256, 0, stream>>>(x, xt);
  // K1: t = silu(bn1(xt @ conv_w^T))
  gemm_ep<0, u16><<<dim3(M_TOT / 128, C_DIM / 128), 256, 0, stream>>>(
      xt, wc, t, C_DIM, C_DIM, nullptr, bn1_g, bn1_b, bn1_m, bn1_v);
  // K2: v = t @ value_w^T + value_b
  gemm_ep<1, u16><<<dim3(M_TOT / 128, C_DIM / 128), 256, 0, stream>>>(
      t, wv, vv, C_DIM, C_DIM, value_b, nullptr, nullptr, nullptr, nullptr);
  // K3: om = t @ offset_w^T + offset_b   (f32, 112 cols)
  gemm_ep<1, float><<<dim3(M_TOT / 128, 1), 256, 0, stream>>>(
      t, wo, om, C_DIM, PADOFF, offset_b, nullptr, nullptr, nullptr, nullptr);
  // K4: deformable bilinear sampling (8 px / block)
  dcn_sample<<<dim3(M_TOT / 8), 256, 0, stream>>>(vv, om, dcn);
  // K5: otmp = silu(bn2(dcn @ out_w^T + out_b))   (bf16 NHWC)
  gemm_ep<2, u16><<<dim3(M_TOT / 128, C_DIM / 128), 256, 0, stream>>>(
      dcn, wout, otmp, C_DIM, C_DIM, out_b, bn2_g, bn2_b, bn2_m, bn2_v);
  // K6: bf16 NHWC -> f32 NCHW (d_out)
  nhwc_to_nchw_f32<<<dim3(C_DIM / 64, HW / 64, N_IMG), 256, 0, stream>>>(otmp, outp);
}

// Round 7
// 313.449 us; speedup vs baseline: 1.4553x; 1.0050x over previous
//
#include <hip/hip_runtime.h>
#include <cstdint>

typedef unsigned short u16;   // bf16 bit pattern
typedef unsigned int   u32;
typedef __attribute__((ext_vector_type(8))) __bf16 bf16x8;
typedef __attribute__((ext_vector_type(4))) float  f32x4;
typedef __attribute__((ext_vector_type(4))) u32    u32x4;

#define N_IMG 4
#define C_DIM 256
#define H_DIM 128
#define W_DIM 128
#define HW    (H_DIM * W_DIM)      // 16384
#define M_TOT (N_IMG * HW)         // 65536
#define CG    64
#define PADOFF 112
#define EPSV  1e-5f

__device__ __forceinline__ u16 f2b(float f) {
  u32 u = __float_as_uint(f);
  u += 0x7fffu + ((u >> 16) & 1u);   // round-to-nearest-even
  return (u16)(u >> 16);
}

// async global->LDS, 16B per lane; LDS dest = wave-uniform base + lane*16
__device__ __forceinline__ void async_cp16(const void* g, void* l) {
  __builtin_amdgcn_global_load_lds(
      (const __attribute__((address_space(1))) void*)g,
      (__attribute__((address_space(3))) void*)l, 16, 0, 0);
}

// cast n f32 -> n bf16, 4 elems/thread
__global__ __launch_bounds__(256) void cast_w(const float* __restrict__ in,
                                              u16* __restrict__ out, int n4) {
  int i = blockIdx.x * 256 + threadIdx.x;
  if (i >= n4) return;
  f32x4 v = reinterpret_cast<const f32x4*>(in)[i];
  u32 lo = (u32)f2b(v[0]) | ((u32)f2b(v[1]) << 16);
  u32 hi = (u32)f2b(v[2]) | ((u32)f2b(v[3]) << 16);
  reinterpret_cast<u32*>(out)[2 * i]     = lo;
  reinterpret_cast<u32*>(out)[2 * i + 1] = hi;
}

// per batch z: in f32 (C, HW) -> out bf16 (HW, C)
__global__ __launch_bounds__(256) void nchw_to_nhwc(const float* __restrict__ in,
                                                    u16* __restrict__ out) {
  __shared__ float tile[64][65];
  const int z = blockIdx.z;
  in  += (size_t)z * C_DIM * HW;
  out += (size_t)z * HW * C_DIM;
  const int p0 = blockIdx.x * 64;   // pixel tile
  const int c0 = blockIdx.y * 64;   // channel tile
  const int t = threadIdx.x;
  const int col = t & 63, rb = t >> 6;
#pragma unroll
  for (int i = 0; i < 16; ++i) {
    int row = rb + i * 4;           // channel within tile
    tile[row][col] = in[(size_t)(c0 + row) * HW + p0 + col];
  }
  __syncthreads();
  const int c = t & 63, pb = t >> 6;
#pragma unroll
  for (int i = 0; i < 16; ++i) {
    int p = pb + i * 4;             // pixel within tile
    out[(size_t)(p0 + p) * C_DIM + c0 + c] = f2b(tile[c][p]);
  }
}

// per batch z: in bf16 (HW, C) -> out f32 (C, HW)   [final output store]
__global__ __launch_bounds__(256) void nhwc_to_nchw_f32(const u16* __restrict__ in,
                                                        float* __restrict__ out) {
  __shared__ float tile[64][65];
  const int z = blockIdx.z;
  in  += (size_t)z * HW * C_DIM;
  out += (size_t)z * C_DIM * HW;
  const int c0 = blockIdx.x * 64;   // channel tile
  const int r0 = blockIdx.y * 64;   // pixel tile
  const int t = threadIdx.x;
  const int colu = t & 31, rbase = t >> 5;
#pragma unroll
  for (int i = 0; i < 8; ++i) {
    int row = rbase + i * 8;        // pixel within tile
    u32 u = *reinterpret_cast<const u32*>(in + (size_t)(r0 + row) * C_DIM + c0 + colu * 2);
    tile[row][colu * 2]     = __uint_as_float(u << 16);
    tile[row][colu * 2 + 1] = __uint_as_float(u & 0xffff0000u);
  }
  __syncthreads();
  const int rr = t & 63, cb = t >> 6;
#pragma unroll
  for (int i = 0; i < 16; ++i) {
    int cc = cb + i * 4;            // channel within tile
    out[(size_t)(c0 + cc) * HW + r0 + rr] = tile[rr][cc];
  }
}

// ---------------------------------------------------------------------------
// GEMM: D[m,n] = epilogue( sum_k A[m,k]*B[n,k] ), async global_load_lds
// staging (m97 2-barrier structure), 128x128 tile, BK=32, 16x16x32 MFMA.
// MODE 0: bn+silu -> Cb bf16 (stride 256)
// MODE 1: fused value+offset: bn-tile<256 -> Cb bf16 +bias; else Cf f32 +bias2
// MODE 2: +bias,bn,silu -> Cb bf16
// ---------------------------------------------------------------------------
template <int MODE>
__global__ __launch_bounds__(256) void gemm_ep(
    const u16* __restrict__ A, const u16* __restrict__ B,
    u16* __restrict__ Cb, float* __restrict__ Cf, int K, int Nreal,
    const float* __restrict__ bias, const float* __restrict__ bias2,
    const float* __restrict__ gamma, const float* __restrict__ beta,
    const float* __restrict__ mean, const float* __restrict__ var) {
  constexpr int BM = 128, BK = 32;
  __shared__ __align__(16) u16 As[BM * BK];
  __shared__ __align__(16) u16 Bs[BM * BK];
  const int tid  = threadIdx.x;
  const int lane = tid & 63;
  const int wave = tid >> 6;
  const int quad = lane >> 4;
  const int l16  = lane & 15;
  const int bm = blockIdx.x * BM;
  const int bn = blockIdx.y * BM;
  const int wm = (wave & 1) * 64;
  const int wn = (wave >> 1) * 64;

  f32x4 acc[4][4] = {};

  for (int ko = 0; ko < K; ko += BK) {
#pragma unroll
    for (int it = 0; it < 2; ++it) {
      int chunk = it * 256 + tid;          // 16B chunk id, 512 per tile
      int r  = chunk >> 2;                 // tile row 0..127
      int kk = (chunk & 3) << 3;           // k offset 0,8,16,24
      const u16* ga = A + (size_t)(bm + r) * K + (ko + kk);
      int br = bn + r; if (br >= Nreal) br = Nreal - 1;   // clamp (N=368 case)
      const u16* gb = B + (size_t)br * K + (ko + kk);
      u16* la = As + (size_t)(it * 256 + wave * 64) * 8;  // wave-uniform base
      u16* lb = Bs + (size_t)(it * 256 + wave * 64) * 8;
      async_cp16(ga, la);
      async_cp16(gb, lb);
    }
    __syncthreads();   // drains vmcnt (async copies) + prior ds_reads
    const bf16x8* Ap = reinterpret_cast<const bf16x8*>(As);
    const bf16x8* Bp = reinterpret_cast<const bf16x8*>(Bs);
    bf16x8 af[4], bfr[4];
#pragma unroll
    for (int mi = 0; mi < 4; ++mi) af[mi] = Ap[(wm + mi * 16 + l16) * 4 + quad];
#pragma unroll
    for (int ni = 0; ni < 4; ++ni) bfr[ni] = Bp[(wn + ni * 16 + l16) * 4 + quad];
#pragma unroll
    for (int mi = 0; mi < 4; ++mi)
#pragma unroll
      for (int ni = 0; ni < 4; ++ni)
        acc[mi][ni] = __builtin_amdgcn_mfma_f32_16x16x32_bf16(
            af[mi], bfr[ni], acc[mi][ni], 0, 0, 0);
    __syncthreads();
  }

#pragma unroll
  for (int ni = 0; ni < 4; ++ni) {
    int n = bn + wn + ni * 16 + l16;
    if constexpr (MODE == 0 || MODE == 2) {
      float sc = gamma[n] * rsqrtf(var[n] + EPSV);
      float sh = beta[n] - mean[n] * sc;
      if constexpr (MODE == 2) sh += bias[n] * sc;
#pragma unroll
      for (int mi = 0; mi < 4; ++mi) {
        int mrow = bm + wm + mi * 16 + quad * 4;
#pragma unroll
        for (int i = 0; i < 4; ++i) {
          float y = acc[mi][ni][i] * sc + sh;
          y = y / (1.f + __expf(-y));   // silu
          Cb[(size_t)(mrow + i) * C_DIM + n] = f2b(y);
        }
      }
    } else {  // MODE 1: fused value(bf16) + offset(f32)
      if (bn < C_DIM) {
        float sh = bias[n];
#pragma unroll
        for (int mi = 0; mi < 4; ++mi) {
          int mrow = bm + wm + mi * 16 + quad * 4;
#pragma unroll
          for (int i = 0; i < 4; ++i)
            Cb[(size_t)(mrow + i) * C_DIM + n] = f2b(acc[mi][ni][i] + sh);
        }
      } else {
        int col = n - C_DIM;
        bool ok = col < PADOFF;
        float sh = ok ? bias2[col] : 0.f;
#pragma unroll
        for (int mi = 0; mi < 4; ++mi) {
          int mrow = bm + wm + mi * 16 + quad * 4;
#pragma unroll
          for (int i = 0; i < 4; ++i)
            if (ok) Cf[(size_t)(mrow + i) * PADOFF + col] = acc[mi][ni][i] + sh;
        }
      }
    }
  }
}

// ---------------------------------------------------------------------------
// Deformable sampling, v3: 16 channels/thread (2x dwordx4 per corner),
// 4 lanes/group, 16 pixels/block; om staged in LDS; clamp+select bounds.
// v: (M, C) NHWC bf16 ; om: (M, 112) f32 [per g: 18 offsets(x,y), 9 masks]
// ---------------------------------------------------------------------------
__global__ __launch_bounds__(256) void dcn_sample(
    const u16* __restrict__ v, const float* __restrict__ om,
    u16* __restrict__ outp) {
  __shared__ float sm[16 * PADOFF];   // 1792 f32 = 7 KiB
  const int tid = threadIdx.x;
  const int m0  = blockIdx.x * 16;
  {
    const float* src = om + (size_t)m0 * PADOFF;
#pragma unroll
    for (int i = 0; i < 7; ++i) sm[tid + i * 256] = src[tid + i * 256];
  }
  __syncthreads();
  const int c4 = tid & 3;            // 16-channel slice within group
  const int g  = (tid >> 2) & 3;
  const int pl = tid >> 4;           // pixel within block
  const int m  = m0 + pl;
  const int n  = m >> 14;            // HW = 2^14
  const int hw = m & (HW - 1);
  const int h = hw >> 7, w = hw & 127;
  const float* p = sm + pl * PADOFF + g * 27;
  const u16* vb = v + (size_t)n * HW * C_DIM + g * CG + c4 * 16;
  float acc[16] = {};
#pragma unroll
  for (int k = 0; k < 9; ++k) {
    const int di = k / 3 - 1, dj = k % 3 - 1;
    float ox = p[2 * k], oy = p[2 * k + 1], mk = p[18 + k];
    float lh = (float)(h + di) + oy;
    float lw = (float)(w + dj) + ox;
    float fh = floorf(lh), fw = floorf(lw);
    float dh = lh - fh, dw = lw - fw;
    int h0 = (int)fh, w0 = (int)fw;
    float wy[2] = {(1.f - dh) * mk, dh * mk};
    float wx[2] = {1.f - dw, dw};
#pragma unroll
    for (int cy = 0; cy < 2; ++cy)
#pragma unroll
      for (int cx = 0; cx < 2; ++cx) {
        int hh = h0 + cy, ww = w0 + cx;
        bool ok = ((u32)hh < (u32)H_DIM) & ((u32)ww < (u32)W_DIM);
        float wt = ok ? wy[cy] * wx[cx] : 0.f;
        int hc = min(max(hh, 0), H_DIM - 1);
        int wc = min(max(ww, 0), W_DIM - 1);
        const u16* q = vb + (size_t)((hc << 7) + wc) * C_DIM;
        u32x4 q0 = *reinterpret_cast<const u32x4*>(q);
        u32x4 q1 = *reinterpret_cast<const u32x4*>(q + 8);
#pragma unroll
        for (int j = 0; j < 4; ++j) {
          acc[2 * j]     += wt * __uint_as_float(q0[j] << 16);
          acc[2 * j + 1] += wt * __uint_as_float(q0[j] & 0xffff0000u);
          acc[8 + 2 * j]     += wt * __uint_as_float(q1[j] << 16);
          acc[8 + 2 * j + 1] += wt * __uint_as_float(q1[j] & 0xffff0000u);
        }
      }
  }
  u32x4 r0, r1;
#pragma unroll
  for (int j = 0; j < 4; ++j) {
    r0[j] = (u32)f2b(acc[2 * j])     | ((u32)f2b(acc[2 * j + 1]) << 16);
    r1[j] = (u32)f2b(acc[8 + 2 * j]) | ((u32)f2b(acc[8 + 2 * j + 1]) << 16);
  }
  u16* o = outp + (size_t)m * C_DIM + g * CG + c4 * 16;
  *reinterpret_cast<u32x4*>(o)     = r0;
  *reinterpret_cast<u32x4*>(o + 8) = r1;
}

// ---------------------------------------------------------------------------
extern "C" void kernel_launch(void* const* d_in, const int* in_sizes, int n_in,
                              void* d_out, int out_size, void* d_ws, size_t ws_size,
                              hipStream_t stream) {
  const float* x        = (const float*)d_in[0];
  const float* conv_w   = (const float*)d_in[1];
  const float* bn1_g    = (const float*)d_in[2];
  const float* bn1_b    = (const float*)d_in[3];
  const float* bn1_m    = (const float*)d_in[4];
  const float* bn1_v    = (const float*)d_in[5];
  const float* value_w  = (const float*)d_in[6];
  const float* value_b  = (const float*)d_in[7];
  const float* offset_w = (const float*)d_in[8];
  const float* offset_b = (const float*)d_in[9];
  const float* out_w    = (const float*)d_in[10];
  const float* out_b    = (const float*)d_in[11];
  const float* bn2_g    = (const float*)d_in[12];
  const float* bn2_b    = (const float*)d_in[13];
  const float* bn2_m    = (const float*)d_in[14];
  const float* bn2_v    = (const float*)d_in[15];

  char* ws = (char*)d_ws;
  u16*   xt   = (u16*)(ws);                    // 32 MiB  (x NHWC bf16)
  u16*   t    = (u16*)(ws + 33554432);         // 32 MiB  (post conv+bn1+silu)
  u16*   vv   = (u16*)(ws + 67108864);         // 32 MiB  (value proj)
  float* om   = (float*)(ws + 100663296);      // 28 MiB  (offset+mask f32)
  u16*   wc   = (u16*)(ws + 130023424);        // conv_w bf16 (128 KiB)
  u16*   wcat = (u16*)(ws + 130154496);        // [value_w; offset_w] bf16 (368x256)
  u16*   wout = (u16*)(ws + 130342912);        // out_w bf16 (128 KiB)
  u16*   dcn  = xt;                            // reuse (xt dead after K1)
  u16*   otmp = t;                             // reuse (t dead after K2)
  float* outp = (float*)d_out;                 // final output is f32

  // W: weights f32 -> bf16 (value+offset concatenated along N)
  cast_w<<<64, 256, 0, stream>>>(conv_w,   wc,           65536 / 4);
  cast_w<<<64, 256, 0, stream>>>(value_w,  wcat,         65536 / 4);
  cast_w<<<28, 256, 0, stream>>>(offset_w, wcat + 65536, (PADOFF * C_DIM) / 4);
  cast_w<<<64, 256, 0, stream>>>(out_w,    wout,         65536 / 4);

  // K0: x f32 NCHW -> bf16 NHWC
  nchw_to_nhwc<<<dim3(HW / 64, C_DIM / 64, N_IMG), 256, 0, stream>>>(x, xt);
  // K1: t = silu(bn1(xt @ conv_w^T))
  gemm_ep<0><<<dim3(M_TOT / 128, 2), 256, 0, stream>>>(
      xt, wc, t, nullptr, C_DIM, C_DIM,
      nullptr, nullptr, bn1_g, bn1_b, bn1_m, bn1_v);
  // K2: fused [vv | om] = t @ [value_w; offset_w]^T + [value_b; offset_b]
  gemm_ep<1><<<dim3(M_TOT / 128, 3), 256, 0, stream>>>(
      t, wcat, vv, om, C_DIM, C_DIM + PADOFF,
      value_b, offset_b, nullptr, nullptr, nullptr, nullptr);
  // K4: deformable bilinear sampling (16 px / block)
  dcn_sample<<<dim3(M_TOT / 16), 256, 0, stream>>>(vv, om, dcn);
  // K5: otmp = silu(bn2(dcn @ out_w^T + out_b))   (bf16 NHWC)
  gemm_ep<2><<<dim3(M_TOT / 128, 2), 256, 0, stream>>>(
      dcn, wout, otmp, nullptr, C_DIM, C_DIM,
      out_b, nullptr, bn2_g, bn2_b, bn2_m, bn2_v);
  // K6: bf16 NHWC -> f32 NCHW (d_out)
  nhwc_to_nchw_f32<<<dim3(C_DIM / 64, HW / 64, N_IMG), 256, 0, stream>>>(otmp, outp);
}